// Round 1
// baseline (411.975 us; speedup 1.0000x reference)
//
#include <hip/hip_runtime.h>
#include <hip/hip_bf16.h>

// Problem constants
#define B_  8
#define CIN 32
#define COUT 16
#define K_  4
#define HID 9
#define HIN 256
#define WIN 256
#define HOUT 512
#define WOUT 512
#define TEMP 34.0f
#define EPS_ 1e-5f

// ---------------------------------------------------------------------------
// Kernel A: pooled[b][c] = mean over HxW of x[b][c]  (== mean of upsampled)
// ---------------------------------------------------------------------------
__global__ __launch_bounds__(256) void pool_kernel(const float* __restrict__ x,
                                                   float* __restrict__ pooled) {
    int bc = blockIdx.x;  // 0..255  (b*32+c)
    const float4* p = (const float4*)(x + (size_t)bc * (HIN * WIN));
    float s = 0.f;
    for (int i = threadIdx.x; i < (HIN * WIN) / 4; i += 256) {
        float4 v = p[i];
        s += v.x + v.y + v.z + v.w;
    }
    // wave64 reduce
    #pragma unroll
    for (int off = 32; off > 0; off >>= 1) s += __shfl_down(s, off);
    __shared__ float red[4];
    if ((threadIdx.x & 63) == 0) red[threadIdx.x >> 6] = s;
    __syncthreads();
    if (threadIdx.x == 0)
        pooled[bc] = (red[0] + red[1] + red[2] + red[3]) * (1.f / (HIN * WIN));
}

// ---------------------------------------------------------------------------
// Kernel B: per-sample attention -> aggregated, BN-folded, parity-combined
// 2x2 weights Wc[b][o][i][py][px][u][v] and bias_eff[b][o].
// ---------------------------------------------------------------------------
__global__ __launch_bounds__(256) void attn_weights_kernel(
    const float* __restrict__ pooled, const float* __restrict__ weight,
    const float* __restrict__ bias, const float* __restrict__ fc1_w,
    const float* __restrict__ fc2_w, const float* __restrict__ fc2_b,
    const float* __restrict__ gamma, const float* __restrict__ beta,
    const float* __restrict__ mean, const float* __restrict__ var,
    float* __restrict__ wc, float* __restrict__ bias_eff) {
    int b = blockIdx.x;
    __shared__ float attn[K_];
    if (threadIdx.x == 0) {
        const float* pb = pooled + b * CIN;
        float h[HID];
        for (int j = 0; j < HID; ++j) {
            float s = 0.f;
            for (int c = 0; c < CIN; ++c) s += pb[c] * fc1_w[j * CIN + c];
            h[j] = fmaxf(s, 0.f);
        }
        float lg[K_];
        float mx = -1e30f;
        for (int k = 0; k < K_; ++k) {
            float s = fc2_b[k];
            for (int j = 0; j < HID; ++j) s += h[j] * fc2_w[k * HID + j];
            lg[k] = s * (1.f / TEMP);
            mx = fmaxf(mx, lg[k]);
        }
        float den = 0.f;
        for (int k = 0; k < K_; ++k) { lg[k] = expf(lg[k] - mx); den += lg[k]; }
        for (int k = 0; k < K_; ++k) attn[k] = lg[k] / den;
    }
    __syncthreads();
    float a0 = attn[0], a1 = attn[1], a2 = attn[2], a3v = attn[3];

    // combined parity weights: 512 (o,i) pairs, 2 per thread
    for (int p = threadIdx.x; p < COUT * CIN; p += 256) {
        int o = p >> 5, i = p & 31;
        float scale = gamma[o] / sqrtf(var[o] + EPS_);
        const float* w0 = weight + ((size_t)(0 * COUT + o) * CIN + i) * 9;
        const int kstr = COUT * CIN * 9;  // 4608
        float a3w[9];
        #pragma unroll
        for (int t = 0; t < 9; ++t)
            a3w[t] = scale * (a0 * w0[t] + a1 * w0[kstr + t] +
                              a2 * w0[2 * kstr + t] + a3v * w0[3 * kstr + t]);
        // row combine: tmp[py][u][kx]
        float tmp[2][2][3];
        #pragma unroll
        for (int kx = 0; kx < 3; ++kx) {
            tmp[0][0][kx] = a3w[0 * 3 + kx];
            tmp[0][1][kx] = a3w[1 * 3 + kx] + a3w[2 * 3 + kx];
            tmp[1][0][kx] = a3w[0 * 3 + kx] + a3w[1 * 3 + kx];
            tmp[1][1][kx] = a3w[2 * 3 + kx];
        }
        float* dst = wc + ((size_t)(b * COUT + o) * CIN + i) * 16;
        #pragma unroll
        for (int py = 0; py < 2; ++py)
            #pragma unroll
            for (int px = 0; px < 2; ++px)
                #pragma unroll
                for (int u = 0; u < 2; ++u)
                    #pragma unroll
                    for (int v = 0; v < 2; ++v) {
                        const float* t = tmp[py][u];
                        float val = (px == 0) ? (v == 0 ? t[0] : t[1] + t[2])
                                              : (v == 0 ? t[0] + t[1] : t[2]);
                        dst[((py * 2 + px) * 2 + u) * 2 + v] = val;
                    }
    }
    if (threadIdx.x < COUT) {
        int o = threadIdx.x;
        float scale = gamma[o] / sqrtf(var[o] + EPS_);
        float shift = beta[o] - mean[o] * scale;
        float s = a0 * bias[0 * COUT + o] + a1 * bias[1 * COUT + o] +
                  a2 * bias[2 * COUT + o] + a3v * bias[3 * COUT + o];
        bias_eff[b * COUT + o] = s * scale + shift;
    }
}

// ---------------------------------------------------------------------------
// Kernel C: fused upsample+conv+BN+ReLU via parity decomposition.
// Block: one (b, o, 64x64-output tile) == 32x32 input-base region.
// Thread (ty,tx) in 16x16: 2x2 bases -> 4x4 outputs; reads a 4x4 LDS patch
// per channel; 64 FMA : 16 LDS reads per channel.
// ---------------------------------------------------------------------------
__global__ __launch_bounds__(256) void conv_kernel(
    const float* __restrict__ x, const float* __restrict__ wc,
    const float* __restrict__ bias_eff, float* __restrict__ out) {
    const int tile = blockIdx.x;           // 0..63
    const int o = blockIdx.y;              // 0..15
    const int b = blockIdx.z;              // 0..7
    const int tile_y = tile >> 3, tile_x = tile & 7;
    const int r0 = tile_y * 32, c0 = tile_x * 32;  // input-base tile origin
    const int tid = threadIdx.x;
    const int ty = tid >> 4, tx = tid & 15;

    __shared__ float wlds[CIN * 16];       // 512 floats: this (b,o)'s weights
    __shared__ float tilebuf[34 * 36];     // one channel's input tile (+halo)

    const float* wsrc = wc + (size_t)(b * COUT + o) * CIN * 16;
    for (int e = tid; e < CIN * 16; e += 256) wlds[e] = wsrc[e];

    float acc[2][2][2][2] = {};  // [br][bc][py][px]
    const float* xb = x + (size_t)b * CIN * (HIN * WIN);

    for (int i = 0; i < CIN; ++i) {
        __syncthreads();  // protect tilebuf overwrite; orders wlds on i==0
        const float* xc = xb + (size_t)i * (HIN * WIN);
        for (int e = tid; e < 34 * 34; e += 256) {
            int rr = e / 34, cc = e - rr * 34;
            int gr = r0 - 1 + rr, gc = c0 - 1 + cc;
            float v = 0.f;
            if ((unsigned)gr < (unsigned)HIN && (unsigned)gc < (unsigned)WIN)
                v = xc[gr * WIN + gc];
            tilebuf[rr * 36 + cc] = v;
        }
        __syncthreads();

        float w[16];
        #pragma unroll
        for (int q = 0; q < 16; ++q) w[q] = wlds[i * 16 + q];

        float in[4][4];
        #pragma unroll
        for (int u = 0; u < 4; ++u)
            #pragma unroll
            for (int v = 0; v < 4; ++v)
                in[u][v] = tilebuf[(2 * ty + u) * 36 + (2 * tx + v)];

        #pragma unroll
        for (int br = 0; br < 2; ++br)
            #pragma unroll
            for (int bc = 0; bc < 2; ++bc)
                #pragma unroll
                for (int py = 0; py < 2; ++py)
                    #pragma unroll
                    for (int px = 0; px < 2; ++px) {
                        float s = acc[br][bc][py][px];
                        #pragma unroll
                        for (int u = 0; u < 2; ++u)
                            #pragma unroll
                            for (int v = 0; v < 2; ++v)
                                s = fmaf(w[((py * 2 + px) * 2 + u) * 2 + v],
                                         in[br + py + u][bc + px + v], s);
                        acc[br][bc][py][px] = s;
                    }
    }

    const float bse = bias_eff[b * COUT + o];
    float* ob = out + (size_t)(b * COUT + o) * (HOUT * WOUT);
    #pragma unroll
    for (int br = 0; br < 2; ++br)
        #pragma unroll
        for (int py = 0; py < 2; ++py) {
            int y = 2 * (r0 + 2 * ty + br) + py;
            #pragma unroll
            for (int bc = 0; bc < 2; ++bc)
                #pragma unroll
                for (int px = 0; px < 2; ++px) {
                    int xo = 2 * (c0 + 2 * tx + bc) + px;
                    ob[y * WOUT + xo] =
                        fmaxf(acc[br][bc][py][px] + bse, 0.f);
                }
        }
}

extern "C" void kernel_launch(void* const* d_in, const int* in_sizes, int n_in,
                              void* d_out, int out_size, void* d_ws, size_t ws_size,
                              hipStream_t stream) {
    const float* x      = (const float*)d_in[0];
    const float* weight = (const float*)d_in[1];
    const float* bias   = (const float*)d_in[2];
    const float* fc1_w  = (const float*)d_in[3];
    const float* fc2_w  = (const float*)d_in[4];
    const float* fc2_b  = (const float*)d_in[5];
    const float* bn_g   = (const float*)d_in[6];
    const float* bn_b   = (const float*)d_in[7];
    const float* bn_m   = (const float*)d_in[8];
    const float* bn_v   = (const float*)d_in[9];
    float* out = (float*)d_out;

    float* ws = (float*)d_ws;
    float* pooled   = ws;            // 256 floats
    float* bias_eff = ws + 256;      // 128 floats
    float* wcbuf    = ws + 512;      // 8*16*32*16 = 65536 floats

    pool_kernel<<<dim3(B_ * CIN), dim3(256), 0, stream>>>(x, pooled);
    attn_weights_kernel<<<dim3(B_), dim3(256), 0, stream>>>(
        pooled, weight, bias, fc1_w, fc2_w, fc2_b, bn_g, bn_b, bn_m, bn_v,
        wcbuf, bias_eff);
    conv_kernel<<<dim3(64, COUT, B_), dim3(256), 0, stream>>>(
        x, wcbuf, bias_eff, out);
}

// Round 2
// 192.487 us; speedup vs baseline: 2.1403x; 2.1403x over previous
//
#include <hip/hip_runtime.h>
#include <hip/hip_bf16.h>

// Problem constants
#define B_  8
#define CIN 32
#define COUT 16
#define OGRP 4          // output channels per block
#define K_  4
#define HID 9
#define HIN 256
#define WIN 256
#define HOUT 512
#define WOUT 512
#define TEMP 34.0f
#define EPS_ 1e-5f
#define PITCH 36

// ---------------------------------------------------------------------------
// Kernel A: pooled[b][c] = mean over HxW of x[b][c]  (== mean of upsampled)
// ---------------------------------------------------------------------------
__global__ __launch_bounds__(256) void pool_kernel(const float* __restrict__ x,
                                                   float* __restrict__ pooled) {
    int bc = blockIdx.x;  // 0..255  (b*32+c)
    const float4* p = (const float4*)(x + (size_t)bc * (HIN * WIN));
    float s = 0.f;
    for (int i = threadIdx.x; i < (HIN * WIN) / 4; i += 256) {
        float4 v = p[i];
        s += v.x + v.y + v.z + v.w;
    }
    #pragma unroll
    for (int off = 32; off > 0; off >>= 1) s += __shfl_down(s, off);
    __shared__ float red[4];
    if ((threadIdx.x & 63) == 0) red[threadIdx.x >> 6] = s;
    __syncthreads();
    if (threadIdx.x == 0)
        pooled[bc] = (red[0] + red[1] + red[2] + red[3]) * (1.f / (HIN * WIN));
}

// ---------------------------------------------------------------------------
// Kernel B: attention -> aggregated, BN-folded, parity-combined 2x2 weights
// ---------------------------------------------------------------------------
__global__ __launch_bounds__(256) void attn_weights_kernel(
    const float* __restrict__ pooled, const float* __restrict__ weight,
    const float* __restrict__ bias, const float* __restrict__ fc1_w,
    const float* __restrict__ fc2_w, const float* __restrict__ fc2_b,
    const float* __restrict__ gamma, const float* __restrict__ beta,
    const float* __restrict__ mean, const float* __restrict__ var,
    float* __restrict__ wc, float* __restrict__ bias_eff) {
    int b = blockIdx.x;
    __shared__ float attn[K_];
    if (threadIdx.x == 0) {
        const float* pb = pooled + b * CIN;
        float h[HID];
        for (int j = 0; j < HID; ++j) {
            float s = 0.f;
            for (int c = 0; c < CIN; ++c) s += pb[c] * fc1_w[j * CIN + c];
            h[j] = fmaxf(s, 0.f);
        }
        float lg[K_];
        float mx = -1e30f;
        for (int k = 0; k < K_; ++k) {
            float s = fc2_b[k];
            for (int j = 0; j < HID; ++j) s += h[j] * fc2_w[k * HID + j];
            lg[k] = s * (1.f / TEMP);
            mx = fmaxf(mx, lg[k]);
        }
        float den = 0.f;
        for (int k = 0; k < K_; ++k) { lg[k] = expf(lg[k] - mx); den += lg[k]; }
        for (int k = 0; k < K_; ++k) attn[k] = lg[k] / den;
    }
    __syncthreads();
    float a0 = attn[0], a1 = attn[1], a2 = attn[2], a3v = attn[3];

    for (int p = threadIdx.x; p < COUT * CIN; p += 256) {
        int o = p >> 5, i = p & 31;
        float scale = gamma[o] / sqrtf(var[o] + EPS_);
        const float* w0 = weight + ((size_t)(0 * COUT + o) * CIN + i) * 9;
        const int kstr = COUT * CIN * 9;  // 4608
        float a3w[9];
        #pragma unroll
        for (int t = 0; t < 9; ++t)
            a3w[t] = scale * (a0 * w0[t] + a1 * w0[kstr + t] +
                              a2 * w0[2 * kstr + t] + a3v * w0[3 * kstr + t]);
        float tmp[2][2][3];
        #pragma unroll
        for (int kx = 0; kx < 3; ++kx) {
            tmp[0][0][kx] = a3w[0 * 3 + kx];
            tmp[0][1][kx] = a3w[1 * 3 + kx] + a3w[2 * 3 + kx];
            tmp[1][0][kx] = a3w[0 * 3 + kx] + a3w[1 * 3 + kx];
            tmp[1][1][kx] = a3w[2 * 3 + kx];
        }
        float* dst = wc + ((size_t)(b * COUT + o) * CIN + i) * 16;
        #pragma unroll
        for (int py = 0; py < 2; ++py)
            #pragma unroll
            for (int px = 0; px < 2; ++px)
                #pragma unroll
                for (int u = 0; u < 2; ++u)
                    #pragma unroll
                    for (int v = 0; v < 2; ++v) {
                        const float* t = tmp[py][u];
                        float val = (px == 0) ? (v == 0 ? t[0] : t[1] + t[2])
                                              : (v == 0 ? t[0] + t[1] : t[2]);
                        dst[((py * 2 + px) * 2 + u) * 2 + v] = val;
                    }
    }
    if (threadIdx.x < COUT) {
        int o = threadIdx.x;
        float scale = gamma[o] / sqrtf(var[o] + EPS_);
        float shift = beta[o] - mean[o] * scale;
        float s = a0 * bias[0 * COUT + o] + a1 * bias[1 * COUT + o] +
                  a2 * bias[2 * COUT + o] + a3v * bias[3 * COUT + o];
        bias_eff[b * COUT + o] = s * scale + shift;
    }
}

// ---------------------------------------------------------------------------
// Kernel C: fused upsample+conv+BN+ReLU via parity decomposition.
// Block: (b, 4-output-channel group, 64x64-output tile == 32x32 input bases).
// Thread (ty,tx) in 16x16: 2x2 bases -> 4x4 outputs per channel, 4 channels.
// Input patch via conflict-free float2 LDS reads; weights via block-uniform
// global reads (scalarized to s_load); float4 coalesced stores.
// ---------------------------------------------------------------------------
__global__ __launch_bounds__(256) void conv_kernel(
    const float* __restrict__ x, const float* __restrict__ wc,
    const float* __restrict__ bias_eff, float* __restrict__ out) {
    const int tile = blockIdx.x;           // 0..63
    const int o0 = blockIdx.y * OGRP;      // 0,4,8,12
    const int b = blockIdx.z;              // 0..7
    const int tile_y = tile >> 3, tile_x = tile & 7;
    const int r0 = tile_y * 32, c0 = tile_x * 32;  // input-base tile origin
    const int tid = threadIdx.x;
    const int ty = tid >> 4, tx = tid & 15;

    __shared__ float tilebuf[34 * PITCH];  // one channel's input tile (+halo)

    float acc[OGRP][2][2][2][2] = {};      // [oo][br][bc][py][px]
    const float* xb = x + (size_t)b * CIN * (HIN * WIN);
    const float* wb = wc + (size_t)(b * COUT + o0) * CIN * 16;

    for (int i = 0; i < CIN; ++i) {
        __syncthreads();  // protect tilebuf overwrite
        const float* xc = xb + (size_t)i * (HIN * WIN);
        #pragma unroll
        for (int e = tid; e < 34 * 34; e += 256) {
            int rr = e / 34, cc = e - rr * 34;
            int gr = r0 - 1 + rr, gc = c0 - 1 + cc;
            float v = 0.f;
            if ((unsigned)gr < (unsigned)HIN && (unsigned)gc < (unsigned)WIN)
                v = xc[gr * WIN + gc];
            tilebuf[rr * PITCH + cc] = v;
        }
        __syncthreads();

        // 4x4 input patch as 8 conflict-free ds_read_b64
        float in[4][4];
        #pragma unroll
        for (int u = 0; u < 4; ++u) {
            #pragma unroll
            for (int vp = 0; vp < 2; ++vp) {
                float2 t = *(const float2*)&tilebuf[(2 * ty + u) * PITCH +
                                                    2 * tx + 2 * vp];
                in[u][2 * vp] = t.x;
                in[u][2 * vp + 1] = t.y;
            }
        }

        #pragma unroll
        for (int oo = 0; oo < OGRP; ++oo) {
            // block-uniform -> s_load (SMEM pipe, no VALU/LDS cost)
            const float* wp = wb + ((size_t)oo * CIN + i) * 16;
            float w[16];
            #pragma unroll
            for (int q = 0; q < 16; ++q) w[q] = wp[q];

            #pragma unroll
            for (int br = 0; br < 2; ++br)
                #pragma unroll
                for (int bc = 0; bc < 2; ++bc)
                    #pragma unroll
                    for (int py = 0; py < 2; ++py)
                        #pragma unroll
                        for (int px = 0; px < 2; ++px) {
                            float s = acc[oo][br][bc][py][px];
                            #pragma unroll
                            for (int u = 0; u < 2; ++u)
                                #pragma unroll
                                for (int v = 0; v < 2; ++v)
                                    s = fmaf(w[((py * 2 + px) * 2 + u) * 2 + v],
                                             in[br + py + u][bc + px + v], s);
                            acc[oo][br][bc][py][px] = s;
                        }
        }
    }

    // Epilogue: bias + ReLU, float4 stores (columns 2c0+4tx+{0..3} contiguous)
    #pragma unroll
    for (int oo = 0; oo < OGRP; ++oo) {
        const float bse = bias_eff[b * COUT + o0 + oo];
        float* ob = out + (size_t)(b * COUT + o0 + oo) * (HOUT * WOUT);
        #pragma unroll
        for (int br = 0; br < 2; ++br)
            #pragma unroll
            for (int py = 0; py < 2; ++py) {
                int y = 2 * (r0 + 2 * ty + br) + py;
                float4 v;
                v.x = fmaxf(acc[oo][br][0][py][0] + bse, 0.f);
                v.y = fmaxf(acc[oo][br][0][py][1] + bse, 0.f);
                v.z = fmaxf(acc[oo][br][1][py][0] + bse, 0.f);
                v.w = fmaxf(acc[oo][br][1][py][1] + bse, 0.f);
                *(float4*)&ob[(size_t)y * WOUT + 2 * c0 + 4 * tx] = v;
            }
    }
}

extern "C" void kernel_launch(void* const* d_in, const int* in_sizes, int n_in,
                              void* d_out, int out_size, void* d_ws, size_t ws_size,
                              hipStream_t stream) {
    const float* x      = (const float*)d_in[0];
    const float* weight = (const float*)d_in[1];
    const float* bias   = (const float*)d_in[2];
    const float* fc1_w  = (const float*)d_in[3];
    const float* fc2_w  = (const float*)d_in[4];
    const float* fc2_b  = (const float*)d_in[5];
    const float* bn_g   = (const float*)d_in[6];
    const float* bn_b   = (const float*)d_in[7];
    const float* bn_m   = (const float*)d_in[8];
    const float* bn_v   = (const float*)d_in[9];
    float* out = (float*)d_out;

    float* ws = (float*)d_ws;
    float* pooled   = ws;            // 256 floats
    float* bias_eff = ws + 256;      // 128 floats
    float* wcbuf    = ws + 512;      // 8*16*32*16 = 65536 floats

    pool_kernel<<<dim3(B_ * CIN), dim3(256), 0, stream>>>(x, pooled);
    attn_weights_kernel<<<dim3(B_), dim3(256), 0, stream>>>(
        pooled, weight, bias, fc1_w, fc2_w, fc2_b, bn_g, bn_b, bn_m, bn_v,
        wcbuf, bias_eff);
    conv_kernel<<<dim3(64, COUT / OGRP, B_), dim3(256), 0, stream>>>(
        x, wcbuf, bias_eff, out);
}